// Round 13
// baseline (1423.502 us; speedup 1.0000x reference)
//
#include <hip/hip_runtime.h>

// ---------- types / helpers ----------
typedef __attribute__((ext_vector_type(8))) _Float16 f16x8;
typedef __attribute__((ext_vector_type(4))) float floatx4;

union HFrag { uint4 u4; f16x8 v; unsigned short s[8]; };
union HS { _Float16 h; unsigned short u; };

__device__ __forceinline__ float bf2f(unsigned short u) {
  return __uint_as_float(((unsigned int)u) << 16);
}
__device__ __forceinline__ float h2f(unsigned short u) { HS z; z.u = u; return (float)z.h; }
__device__ __forceinline__ unsigned short f2h(float f) { HS z; z.h = (_Float16)f; return z.u; }
__device__ __forceinline__ float sigmf(float x) { return 1.0f / (1.0f + expf(-x)); }

// dtype-agnostic input load: f32 ? float : bf16
__device__ __forceinline__ float ldi(const void* p, long i, bool f32) {
  return f32 ? ((const float*)p)[i] : bf2f(((const unsigned short*)p)[i]);
}

// async global->LDS DMA, 16B per lane. LDS dest = wave-uniform base + lane*16.
__device__ __forceinline__ void dma16(unsigned short* lds, const unsigned short* g) {
  __builtin_amdgcn_global_load_lds(
      (const __attribute__((address_space(1))) unsigned int*)g,
      (__attribute__((address_space(3))) unsigned int*)lds,
      16, 0, 0);
}

// wave-local waits (gfx9 encoding: vm [3:0]|[15:14], exp [6:4], lgkm [11:8])
#define WAIT_VM8()   __builtin_amdgcn_s_waitcnt(0x0F78)
#define WAIT_VM4()   __builtin_amdgcn_s_waitcnt(0x0F74)
#define WAIT_VM0()   __builtin_amdgcn_s_waitcnt(0x0F70)
#define WAIT_LGKM0() __builtin_amdgcn_s_waitcnt(0xC07F)

#define NNODES 32000
#define NEDGES 80000
#define NGRAPH 1000

#define MFMA_F16 __builtin_amdgcn_mfma_f32_16x16x32_f16

// ---------- dtype detect ----------
__global__ __launch_bounds__(256) void detect_kernel(
    const unsigned short* __restrict__ nf, int* __restrict__ flag) {
  __shared__ float sm[256];
  float m = 0.f;
  for (int i = threadIdx.x; i < 4096; i += 256) {
    float v = fabsf(bf2f(nf[i]));
    if (isfinite(v)) m = fmaxf(m, v);
    else m = 1e30f;
  }
  sm[threadIdx.x] = m;
  __syncthreads();
  if (threadIdx.x == 0) {
    float mm = 0.f;
    for (int i = 0; i < 256; ++i) mm = fmaxf(mm, sm[i]);
    flag[0] = (mm > 1e6f) ? 1 : 0;
  }
}

// ---------- prep: GRU weights -> fp16 [192][64] (j-major, transposed) ----------
__global__ __launch_bounds__(256) void prep_kernel(
    const int* __restrict__ dflag,
    const void* __restrict__ Wx, const void* __restrict__ Wh,
    const void* __restrict__ bx, const void* __restrict__ bh,
    const void* __restrict__ bconv,
    unsigned short* __restrict__ WxH, unsigned short* __restrict__ WhH,
    float* __restrict__ bxf, float* __restrict__ bhf, float* __restrict__ bconvf) {
  bool f32 = dflag[0] != 0;
  int idx = blockIdx.x * 256 + threadIdx.x;   // grid 48 -> 12288 = 192*64
  int j = idx >> 6, k = idx & 63;
  WxH[idx] = f2h(ldi(Wx, k * 192 + j, f32));
  WhH[idx] = f2h(ldi(Wh, k * 192 + j, f32));
  if (idx < 192) { bxf[idx] = ldi(bx, idx, f32); bhf[idx] = ldi(bh, idx, f32); }
  if (idx < 64) bconvf[idx] = ldi(bconv, idx, f32);
}

// ---------- node projection: h = relu(nf @ Wp + bp) ----------
__global__ __launch_bounds__(256) void nodeproj_kernel(
    const int* __restrict__ dflag,
    const void* __restrict__ nf, const void* __restrict__ Wp,
    const void* __restrict__ bp, float* __restrict__ hstate) {
  bool f32 = dflag[0] != 0;
  int lane = threadIdx.x & 63;
  int n = blockIdx.x * 4 + (threadIdx.x >> 6);
  float acc = ldi(bp, lane, f32);
  for (int k = 0; k < 74; ++k)
    acc += ldi(nf, (long)n * 74 + k, f32) * ldi(Wp, k * 64 + lane, f32);
  hstate[n * 64 + lane] = fmaxf(acc, 0.0f);
}

// ---------- We2Hsw: fp16, layout [d][o][cc][j], cc = (k/8) ^ (o&15) ----------
__global__ __launch_bounds__(256) void we2h_kernel(
    const int* __restrict__ dflag,
    const void* __restrict__ We2, unsigned short* __restrict__ We2Hsw) {
  bool f32 = dflag[0] != 0;
  int idx = blockIdx.x * 256 + threadIdx.x;  // grid 2048 -> 524288
  int j = idx & 7;
  int cc = (idx >> 3) & 15;
  int o = (idx >> 7) & 63;
  int d = idx >> 13;
  int k = ((cc ^ (o & 15)) << 3) | j;
  We2Hsw[idx] = f2h(ldi(We2, (long)k * 4096 + d * 64 + o, f32));
}

// ---------- CSR build (once per launch; dst is launch-invariant) ----------
__global__ __launch_bounds__(256) void count_kernel(
    const int* __restrict__ dst, int* __restrict__ cnt) {
  int e = blockIdx.x * 256 + threadIdx.x;
  if (e < NEDGES) atomicAdd(&cnt[dst[e]], 1);
}

__global__ __launch_bounds__(256) void scan_kernel(
    const int* __restrict__ cnt, int* __restrict__ row_ptr, int* __restrict__ cur) {
  __shared__ int part[256];
  int t = threadIdx.x;
  int base = t * 125;              // 256*125 = 32000
  int s = 0;
  for (int i = 0; i < 125; ++i) s += cnt[base + i];
  part[t] = s;
  __syncthreads();
  if (t == 0) {
    int run = 0;
    for (int i = 0; i < 256; ++i) { int v = part[i]; part[i] = run; run += v; }
  }
  __syncthreads();
  int run = part[t];
  for (int i = 0; i < 125; ++i) {
    row_ptr[base + i] = run;
    cur[base + i] = run;
    run += cnt[base + i];
  }
  if (t == 255) row_ptr[32000] = run;
}

__global__ __launch_bounds__(256) void fill_kernel(
    const int* __restrict__ dst, int* __restrict__ cur, int* __restrict__ eidx) {
  int e = blockIdx.x * 256 + threadIdx.x;
  if (e < NEDGES) { int p = atomicAdd(&cur[dst[e]], 1); eidx[p] = e; }
}

// ---------- fused message passing: 64 edges/block, depth-3 vmcnt pipeline -------
// Changes vs r12: (1) be2 term hoisted out of the d-loop — computed once per
// wave via 8 MFMAs (A = be2t fp16, B = fp16(h)), initializing msg accumulators;
// (2) register double-buffered A-frags: slice d+1's ds_reads issue at the end
// of iter d and overlap iter d+1's VALU; lgkm0 sits after the MFMA block and
// guards the DMA write-after-read hazard explicitly.
__global__ __launch_bounds__(256, 2) void msg_fused_kernel(
    const int* __restrict__ dflag,
    const float* __restrict__ hstate,
    const void* __restrict__ ef, const void* __restrict__ We1,
    const void* __restrict__ be1, const void* __restrict__ be2,
    const unsigned short* __restrict__ We2Hsw,
    const int* __restrict__ src, const int* __restrict__ eidx,
    float* __restrict__ msgbuf) {
  bool f32 = dflag[0] != 0;
  __shared__ __align__(16) unsigned short u_s[64][136];   // 17408 B (aliased as buf2)
  __shared__ float h_s[64][65];                           // 16640 B
  __shared__ __align__(16) unsigned short be2t[64][72];   // 9216 B (fp16, [o][d])
  __shared__ int ssrc[64];
  __shared__ int seidx[64];
  __shared__ __align__(16) unsigned short wbuf[2][8192];  // 32768 B
  float* ef_s = (float*)&wbuf[0][0];        // 768 floats  (dead before DMA)
  float* we1_s = (float*)&wbuf[0][2048];    // 1536 floats
  float* be1_s = (float*)&wbuf[1][0];       // 128 floats

  int t = threadIdx.x;
  int e0 = blockIdx.x * 64;                 // 1250 blocks
  int lane = t & 63, w = t >> 6;

  if (t < 64) { int e = eidx[e0 + t]; seidx[t] = e; ssrc[t] = src[e]; }
  for (int i = t; i < 1536; i += 256) we1_s[i] = ldi(We1, i, f32);
  if (t < 128) be1_s[t] = ldi(be1, t, f32);
  for (int i = t; i < 4096; i += 256) {
    int d = i >> 6, o = i & 63;
    be2t[o][d] = f2h(ldi(be2, i, f32));     // transpose: [d][o] -> [o][d]
  }
  __syncthreads();
  for (int i = t; i < 768; i += 256) {
    int slot = i / 12, k = i - slot * 12;
    ef_s[i] = ldi(ef, (long)seidx[slot] * 12 + k, f32);
  }
  __syncthreads();

#pragma unroll
  for (int i = 0; i < 32; ++i) {            // 8192 = 64 edges x 128 cols
    int idx = t + i * 256;
    int row = idx >> 7, col = idx & 127;
    float acc = be1_s[col];
#pragma unroll
    for (int k = 0; k < 12; ++k) acc += ef_s[row * 12 + k] * we1_s[k * 128 + col];
    u_s[row][col] = f2h(fmaxf(acc, 0.f));
  }
#pragma unroll
  for (int i = 0; i < 16; ++i) {            // 4096 = 64 rows x 64 cols
    int idx = t + i * 256;
    int row = idx >> 6, col = idx & 63;
    h_s[row][col] = hstate[(size_t)ssrc[row] * 64 + col];
  }
  __syncthreads();                          // scratch (wbuf) dead from here

  // ---- prefetch slices 0,1 into wbuf[0..1] (wave-private quarters) ----
  unsigned short* buf0 = &wbuf[0][0];
  unsigned short* buf1 = &wbuf[1][0];
  unsigned short* buf2 = &u_s[0][0];
  {
    const unsigned short* g0 = We2Hsw + w * 2048 + lane * 8;
    unsigned short* l0 = buf0 + w * 2048;
    dma16(l0, g0); dma16(l0 + 512, g0 + 512);
    dma16(l0 + 1024, g0 + 1024); dma16(l0 + 1536, g0 + 1536);
    const unsigned short* g1 = g0 + 8192;
    unsigned short* l1 = buf1 + w * 2048;
    dma16(l1, g1); dma16(l1 + 512, g1 + 512);
    dma16(l1 + 1024, g1 + 1024); dma16(l1 + 1536, g1 + 1536);
  }

  // ---- B fragments from u_s + be2-hoist MFMA (msg init) ----
  int o0 = w * 16;
  int c = lane & 15, q = lane >> 4;
  HFrag ub[4][4];
#pragma unroll
  for (int g = 0; g < 4; ++g)
#pragma unroll
    for (int kk = 0; kk < 4; ++kk)
      ub[g][kk].u4 = *(const uint4*)&u_s[g * 16 + c][q * 8 + kk * 32];
  floatx4 msg[4];
#pragma unroll
  for (int g = 0; g < 4; ++g) msg[g] = (floatx4){0.f, 0.f, 0.f, 0.f};
  // msg += (h @ be2)[edges, o-slice] : A = be2t[o][d], B = fp16(h[n][d])
#pragma unroll
  for (int kc = 0; kc < 2; ++kc) {
    int kof = kc * 32 + q * 8;
    HFrag abe;
    abe.u4 = *(const uint4*)&be2t[o0 + c][kof];
#pragma unroll
    for (int g = 0; g < 4; ++g) {
      HFrag bh;
#pragma unroll
      for (int j = 0; j < 8; ++j) bh.s[j] = f2h(h_s[g * 16 + c][kof + j]);
      msg[g] = MFMA_F16(abe.v, bh.v, msg[g], 0, 0, 0);
    }
  }
  int rowb = (o0 + c) * 16;

  __syncthreads();                          // all waves' u_s reads drained -> buf2 free
  {
    const unsigned short* g2 = We2Hsw + 2 * 8192 + w * 2048 + lane * 8;
    unsigned short* l2 = buf2 + w * 2048;
    dma16(l2, g2); dma16(l2 + 512, g2 + 512);
    dma16(l2 + 1024, g2 + 1024); dma16(l2 + 1536, g2 + 1536);
  }

  // ---- pre-read A-frags for d=0 ----
  WAIT_VM8();                               // slice 0 complete (1,2 in flight)
  HFrag c0, c1, c2, c3, n0, n1, n2, n3;
  c0.u4 = *(const uint4*)&buf0[(rowb + ((0 * 4 + q) ^ c)) * 8];
  c1.u4 = *(const uint4*)&buf0[(rowb + ((1 * 4 + q) ^ c)) * 8];
  c2.u4 = *(const uint4*)&buf0[(rowb + ((2 * 4 + q) ^ c)) * 8];
  c3.u4 = *(const uint4*)&buf0[(rowb + ((3 * 4 + q) ^ c)) * 8];

  // ---- depth-3 d-loop, register double-buffered ----
  for (int d = 0; d < 64; ++d) {
    float hv0 = h_s[0 * 16 + c][d];
    float hv1 = h_s[1 * 16 + c][d];
    float hv2 = h_s[2 * 16 + c][d];
    float hv3 = h_s[3 * 16 + c][d];
    floatx4 w0 = {0.f, 0.f, 0.f, 0.f}, w1 = {0.f, 0.f, 0.f, 0.f};
    floatx4 w2 = {0.f, 0.f, 0.f, 0.f}, w3 = {0.f, 0.f, 0.f, 0.f};
    w0 = MFMA_F16(c0.v, ub[0][0].v, w0, 0, 0, 0);
    w1 = MFMA_F16(c0.v, ub[1][0].v, w1, 0, 0, 0);
    w2 = MFMA_F16(c0.v, ub[2][0].v, w2, 0, 0, 0);
    w3 = MFMA_F16(c0.v, ub[3][0].v, w3, 0, 0, 0);
    w0 = MFMA_F16(c1.v, ub[0][1].v, w0, 0, 0, 0);
    w1 = MFMA_F16(c1.v, ub[1][1].v, w1, 0, 0, 0);
    w2 = MFMA_F16(c1.v, ub[2][1].v, w2, 0, 0, 0);
    w3 = MFMA_F16(c1.v, ub[3][1].v, w3, 0, 0, 0);
    w0 = MFMA_F16(c2.v, ub[0][2].v, w0, 0, 0, 0);
    w1 = MFMA_F16(c2.v, ub[1][2].v, w1, 0, 0, 0);
    w2 = MFMA_F16(c2.v, ub[2][2].v, w2, 0, 0, 0);
    w3 = MFMA_F16(c2.v, ub[3][2].v, w3, 0, 0, 0);
    w0 = MFMA_F16(c3.v, ub[0][3].v, w0, 0, 0, 0);
    w1 = MFMA_F16(c3.v, ub[1][3].v, w1, 0, 0, 0);
    w2 = MFMA_F16(c3.v, ub[2][3].v, w2, 0, 0, 0);
    w3 = MFMA_F16(c3.v, ub[3][3].v, w3, 0, 0, 0);
    WAIT_LGKM0();                           // cur reads + h drained (WAR guard)
    int m3 = d % 3;
    unsigned short* fb = (m3 == 0) ? buf0 : (m3 == 1) ? buf1 : buf2;
    if (d <= 60) {
      const unsigned short* g = We2Hsw + (d + 3) * 8192 + w * 2048 + lane * 8;
      unsigned short* l = fb + w * 2048;
      dma16(l, g); dma16(l + 512, g + 512);
      dma16(l + 1024, g + 1024); dma16(l + 1536, g + 1536);
      WAIT_VM8();                           // slice d+1 complete
    } else if (d == 61) WAIT_VM4();
    else if (d == 62) WAIT_VM0();
    if (d < 63) {
      int n3i = (d + 1) % 3;
      unsigned short* nb = (n3i == 0) ? buf0 : (n3i == 1) ? buf1 : buf2;
      n0.u4 = *(const uint4*)&nb[(rowb + ((0 * 4 + q) ^ c)) * 8];
      n1.u4 = *(const uint4*)&nb[(rowb + ((1 * 4 + q) ^ c)) * 8];
      n2.u4 = *(const uint4*)&nb[(rowb + ((2 * 4 + q) ^ c)) * 8];
      n3.u4 = *(const uint4*)&nb[(rowb + ((3 * 4 + q) ^ c)) * 8];
    }
#pragma unroll
    for (int r = 0; r < 4; ++r) {
      msg[0][r] += hv0 * w0[r];
      msg[1][r] += hv1 * w1[r];
      msg[2][r] += hv2 * w2[r];
      msg[3][r] += hv3 * w3[r];
    }
    c0 = n0; c1 = n1; c2 = n2; c3 = n3;
  }

#pragma unroll
  for (int g = 0; g < 4; ++g) {
    int slot = g * 16 + c;
    float4 st;
    st.x = msg[g][0]; st.y = msg[g][1]; st.z = msg[g][2]; st.w = msg[g][3];
    *(float4*)(msgbuf + (size_t)(e0 + slot) * 64 + o0 + q * 4) = st;
  }
}

// ---------- GRU step: MFMA gates (fp16, X hi/lo split) + fused CSR gather ------
__global__ __launch_bounds__(256, 2) void gru_kernel(
    float* __restrict__ hstate, const float* __restrict__ msgbuf,
    const int* __restrict__ row_ptr,
    const unsigned short* __restrict__ WxH, const unsigned short* __restrict__ WhH,
    const float* __restrict__ bxf, const float* __restrict__ bhf,
    const float* __restrict__ bconvf) {
  __shared__ __align__(16) unsigned short Xhi[64][72];   // 9216 B
  __shared__ __align__(16) unsigned short Xlo[64][72];   // 9216 B
  __shared__ __align__(16) unsigned short Hh[64][72];    // 9216 B
  __shared__ unsigned short SRZ[128][68];                // 17408 B (fp16 sig(r/z))
  __shared__ float GXn[64][66];                          // 16896 B
  __shared__ float GHn[64][66];                          // 16896 B
  int t = threadIdx.x;
  int nb = blockIdx.x * 64;                              // 500 blocks

#pragma unroll
  for (int i = 0; i < 16; ++i) {
    int idx = t + i * 256;
    int n = idx >> 6, c = idx & 63;
    int node = nb + n;
    float a = bconvf[c];
    int p0 = row_ptr[node], p1 = row_ptr[node + 1];
    for (int p = p0; p < p1; ++p) a += msgbuf[(size_t)p * 64 + c];
    a = fmaxf(a, 0.f);
    HS hi; hi.h = (_Float16)a;
    Xhi[n][c] = hi.u;
    Xlo[n][c] = f2h(a - (float)hi.h);
    Hh[n][c] = f2h(hstate[(size_t)node * 64 + c]);
  }
  __syncthreads();

  int lane = t & 63, w = t >> 6;
  int c16 = lane & 15, q = lane >> 4;
  floatx4 gx[3][4], gh[3][4];
#pragma unroll
  for (int jt = 0; jt < 3; ++jt)
#pragma unroll
    for (int nt = 0; nt < 4; ++nt) {
      gx[jt][nt] = (floatx4){0.f, 0.f, 0.f, 0.f};
      gh[jt][nt] = (floatx4){0.f, 0.f, 0.f, 0.f};
    }
#pragma unroll
  for (int kc = 0; kc < 2; ++kc) {
    int kof = kc * 32 + q * 8;
    HFrag ax[3], ah[3];
#pragma unroll
    for (int jt = 0; jt < 3; ++jt) {
      long off = (long)((w * 3 + jt) * 16 + c16) * 64 + kof;
      ax[jt].u4 = *(const uint4*)(WxH + off);
      ah[jt].u4 = *(const uint4*)(WhH + off);
    }
    HFrag bxh[4], bxl[4], bhf_[4];
#pragma unroll
    for (int nt = 0; nt < 4; ++nt) {
      int n = nt * 16 + c16;
      bxh[nt].u4 = *(const uint4*)&Xhi[n][kof];
      bxl[nt].u4 = *(const uint4*)&Xlo[n][kof];
      bhf_[nt].u4 = *(const uint4*)&Hh[n][kof];
    }
#pragma unroll
    for (int jt = 0; jt < 3; ++jt)
#pragma unroll
      for (int nt = 0; nt < 4; ++nt) {
        gx[jt][nt] = MFMA_F16(ax[jt].v, bxh[nt].v, gx[jt][nt], 0, 0, 0);
        gx[jt][nt] = MFMA_F16(ax[jt].v, bxl[nt].v, gx[jt][nt], 0, 0, 0);
        gh[jt][nt] = MFMA_F16(ah[jt].v, bhf_[nt].v, gh[jt][nt], 0, 0, 0);
      }
  }

#pragma unroll
  for (int jt = 0; jt < 3; ++jt) {
#pragma unroll
    for (int rr = 0; rr < 4; ++rr) {
      int j = (w * 3 + jt) * 16 + q * 4 + rr;
      float bxv = bxf[j], bhv = bhf[j];
#pragma unroll
      for (int nt = 0; nt < 4; ++nt) {
        int n = nt * 16 + c16;
        float vx = gx[jt][nt][rr] + bxv;
        float vh = gh[jt][nt][rr] + bhv;
        if (j < 128) {
          SRZ[j][n] = f2h(sigmf(vx + vh));
        } else {
          GXn[j - 128][n] = vx;
          GHn[j - 128][n] = vh;
        }
      }
    }
  }
  __syncthreads();

#pragma unroll
  for (int i = 0; i < 16; ++i) {
    int idx = t + i * 256;
    int n = idx >> 6, f = idx & 63;
    float r = h2f(SRZ[f][n]);
    float z = h2f(SRZ[64 + f][n]);
    float ng = tanhf(GXn[f][n] + r * GHn[f][n]);
    size_t gi = (size_t)(nb + n) * 64 + f;
    float ho = hstate[gi];
    hstate[gi] = (1.0f - z) * ng + z * ho;
  }
}

// ---------- Set2Set fused: 3-layer LSTM + attention, 4 graphs per block ----------
__global__ __launch_bounds__(256) void s2s_kernel(
    const int* __restrict__ dflag,
    const float* __restrict__ hstate,
    float* __restrict__ q_star, float* __restrict__ hsv, float* __restrict__ csv,
    const void* Wx0, const void* Wh0, const void* bx0, const void* bh0,
    const void* Wx1, const void* Wh1, const void* bx1, const void* bh1,
    const void* Wx2, const void* Wh2, const void* bx2, const void* bh2) {
  bool f32 = dflag[0] != 0;
  __shared__ float xq[4][128];
  __shared__ float hh[4][64];
  __shared__ float gates[4][256];
  __shared__ float al[4][32];
  int g0 = blockIdx.x * 4;
  int t = threadIdx.x;
  const void* Wx[3] = {Wx0, Wx1, Wx2};
  const void* Wh[3] = {Wh0, Wh1, Wh2};
  const void* bx[3] = {bx0, bx1, bx2};
  const void* bh[3] = {bh0, bh1, bh2};
  for (int i = t; i < 512; i += 256) xq[i >> 7][i & 127] = q_star[g0 * 128 + i];
  for (int l = 0; l < 3; ++l) {
    int fi = (l == 0) ? 128 : 64;
    hh[t >> 6][t & 63] = hsv[l * 64000 + g0 * 64 + t];
    __syncthreads();
    float bsum = ldi(bx[l], t, f32) + ldi(bh[l], t, f32);
    float a0 = bsum, a1 = bsum, a2 = bsum, a3 = bsum;
    for (int k = 0; k < fi; ++k) {
      float wv = ldi(Wx[l], (long)k * 256 + t, f32);
      a0 += xq[0][k] * wv;
      a1 += xq[1][k] * wv;
      a2 += xq[2][k] * wv;
      a3 += xq[3][k] * wv;
    }
    for (int k = 0; k < 64; ++k) {
      float wv = ldi(Wh[l], (long)k * 256 + t, f32);
      a0 += hh[0][k] * wv;
      a1 += hh[1][k] * wv;
      a2 += hh[2][k] * wv;
      a3 += hh[3][k] * wv;
    }
    gates[0][t] = a0; gates[1][t] = a1; gates[2][t] = a2; gates[3][t] = a3;
    __syncthreads();
    {
      int gg = t >> 6, tt = t & 63;
      float ig = sigmf(gates[gg][tt]);
      float fg = sigmf(gates[gg][64 + tt]);
      float gv = tanhf(gates[gg][128 + tt]);
      float og = sigmf(gates[gg][192 + tt]);
      long ci = (long)l * 64000 + (g0 + gg) * 64 + tt;
      float cc = fg * csv[ci] + ig * gv;
      float hn = og * tanhf(cc);
      csv[ci] = cc;
      hsv[ci] = hn;
      xq[gg][tt] = hn;
    }
    __syncthreads();
  }
  int gg = t >> 6, tt = t & 63;
  int g = g0 + gg;
  float qv_ = xq[gg][tt];
  {
    int n = tt & 31, half = tt >> 5;
    const float* hrow = hstate + (size_t)(g * 32 + n) * 64 + half * 32;
    const float* qp = &xq[gg][half * 32];
    float p = 0.f;
#pragma unroll
    for (int k = 0; k < 32; ++k) p += hrow[k] * qp[k];
    p += __shfl_xor(p, 32, 64);
    if (half == 0) {
      float m = p;
#pragma unroll
      for (int s2 = 1; s2 < 32; s2 <<= 1) m = fmaxf(m, __shfl_xor(m, s2, 32));
      float e = expf(p - m);
      float s = e;
#pragma unroll
      for (int s2 = 1; s2 < 32; s2 <<= 1) s += __shfl_xor(s, s2, 32);
      al[gg][n] = e / s;
    }
  }
  float acc = 0.f;
#pragma unroll 8
  for (int n = 0; n < 32; ++n)
    acc += al[gg][n] * hstate[(size_t)(g * 32 + n) * 64 + tt];
  q_star[g * 128 + tt] = qv_;
  q_star[g * 128 + 64 + tt] = acc;
}

// ---------- head: FP32 outputs ----------
__global__ __launch_bounds__(64) void head_kernel(
    const int* __restrict__ dflag,
    const float* __restrict__ q_star,
    const void* __restrict__ Wout1, const void* __restrict__ bout1,
    const void* __restrict__ Wout2, const void* __restrict__ bout2,
    float* __restrict__ out) {
  bool f32 = dflag[0] != 0;
  __shared__ float qs[128];
  int g = blockIdx.x;
  int t = threadIdx.x;
  qs[t] = q_star[g * 128 + t];
  qs[64 + t] = q_star[g * 128 + 64 + t];
  __syncthreads();
  float acc = ldi(bout1, t, f32);
#pragma unroll
  for (int k = 0; k < 128; ++k) acc += qs[k] * ldi(Wout1, k * 64 + t, f32);
  acc = fmaxf(acc, 0.0f);
  float p = acc * ldi(Wout2, t, f32);
#pragma unroll
  for (int m = 1; m < 64; m <<= 1) p += __shfl_xor(p, m, 64);
  if (t == 0) out[g] = p + ldi(bout2, 0, f32);
  out[1000 + g * 128 + t] = qs[t];
  out[1000 + g * 128 + 64 + t] = qs[64 + t];
}

// ---------- launch ----------
extern "C" void kernel_launch(void* const* d_in, const int* in_sizes, int n_in,
                              void* d_out, int out_size, void* d_ws, size_t ws_size,
                              hipStream_t stream) {
  (void)in_sizes; (void)n_in; (void)out_size; (void)ws_size;
  const void* node_feats = d_in[0];
  const void* edge_feats = d_in[1];
  const int* src = (const int*)d_in[2];
  const int* dst = (const int*)d_in[3];
  const void* Wp = d_in[5];
  const void* bp = d_in[6];
  const void* We1 = d_in[7];
  const void* be1 = d_in[8];
  const void* We2 = d_in[9];
  const void* be2 = d_in[10];
  const void* b_conv = d_in[11];
  const void* gWx = d_in[12];
  const void* gWh = d_in[13];
  const void* gbx = d_in[14];
  const void* gbh = d_in[15];
  const void* Wout1 = d_in[16];
  const void* bout1 = d_in[17];
  const void* Wout2 = d_in[18];
  const void* bout2 = d_in[19];

  // workspace layout (~33 MB; proven-mapped region >= 44.5 MB)
  int* dflag = (int*)d_ws;                                    // 64 ints reserved
  float* hstate = (float*)d_ws + 64;                          // 32000*64 f32
  float* msgbuf = hstate + NNODES * 64;                       // 80000*64 f32
  unsigned short* We2Hsw = (unsigned short*)(msgbuf + (size_t)NEDGES * 64); // 524288 fp16
  unsigned short* WxH = We2Hsw + 524288;                      // 12288 fp16
  unsigned short* WhH = WxH + 12288;                          // 12288 fp16
  float* bxf = (float*)(WhH + 12288);                         // 192
  float* bhf = bxf + 192;                                     // 192
  float* bconvf = bhf + 192;                                  // 64
  float* q_star = bconvf + 64;                                // 1000*128
  float* hsv = q_star + 128000;                               // 3*1000*64
  float* csv = hsv + 192000;                                  // 3*1000*64
  int* row_ptr = (int*)(csv + 192000);                        // 32001
  int* cur = row_ptr + 32001;                                 // 32000
  int* cnt = cur + 32000;                                     // 32000
  int* eidx = cnt + 32000;                                    // 80000

  (void)hipMemsetAsync(q_star, 0, (size_t)(128000 + 192000 + 192000) * sizeof(float), stream);
  (void)hipMemsetAsync(cnt, 0, (size_t)NNODES * sizeof(int), stream);

  detect_kernel<<<1, 256, 0, stream>>>((const unsigned short*)node_feats, dflag);
  prep_kernel<<<48, 256, 0, stream>>>(dflag, gWx, gWh, gbx, gbh, b_conv,
                                      WxH, WhH, bxf, bhf, bconvf);
  nodeproj_kernel<<<NNODES / 4, 256, 0, stream>>>(dflag, node_feats, Wp, bp, hstate);
  we2h_kernel<<<2048, 256, 0, stream>>>(dflag, We2, We2Hsw);

  count_kernel<<<(NEDGES + 255) / 256, 256, 0, stream>>>(dst, cnt);
  scan_kernel<<<1, 256, 0, stream>>>(cnt, row_ptr, cur);
  fill_kernel<<<(NEDGES + 255) / 256, 256, 0, stream>>>(dst, cur, eidx);

  for (int step = 0; step < 6; ++step) {
    msg_fused_kernel<<<NEDGES / 64, 256, 0, stream>>>(
        dflag, hstate, edge_feats, We1, be1, be2, We2Hsw, src, eidx, msgbuf);
    gru_kernel<<<NNODES / 64, 256, 0, stream>>>(hstate, msgbuf, row_ptr,
                                                WxH, WhH, bxf, bhf, bconvf);
  }
  for (int s = 0; s < 6; ++s) {
    s2s_kernel<<<NGRAPH / 4, 256, 0, stream>>>(dflag, hstate, q_star, hsv, csv,
        d_in[20], d_in[21], d_in[22], d_in[23],
        d_in[24], d_in[25], d_in[26], d_in[27],
        d_in[28], d_in[29], d_in[30], d_in[31]);
  }
  head_kernel<<<NGRAPH, 64, 0, stream>>>(dflag, q_star, Wout1, bout1, Wout2, bout2,
                                         (float*)d_out);
}

// Round 14
// 1356.537 us; speedup vs baseline: 1.0494x; 1.0494x over previous
//
#include <hip/hip_runtime.h>

// ---------- types / helpers ----------
typedef __attribute__((ext_vector_type(8))) _Float16 f16x8;
typedef __attribute__((ext_vector_type(4))) float floatx4;

union HFrag { uint4 u4; f16x8 v; unsigned short s[8]; };
union HS { _Float16 h; unsigned short u; };

__device__ __forceinline__ float bf2f(unsigned short u) {
  return __uint_as_float(((unsigned int)u) << 16);
}
__device__ __forceinline__ float h2f(unsigned short u) { HS z; z.u = u; return (float)z.h; }
__device__ __forceinline__ unsigned short f2h(float f) { HS z; z.h = (_Float16)f; return z.u; }
__device__ __forceinline__ float sigmf(float x) { return 1.0f / (1.0f + expf(-x)); }

// dtype-agnostic input load: f32 ? float : bf16
__device__ __forceinline__ float ldi(const void* p, long i, bool f32) {
  return f32 ? ((const float*)p)[i] : bf2f(((const unsigned short*)p)[i]);
}

// async global->LDS DMA, 16B per lane. LDS dest = wave-uniform base + lane*16.
__device__ __forceinline__ void dma16(unsigned short* lds, const unsigned short* g) {
  __builtin_amdgcn_global_load_lds(
      (const __attribute__((address_space(1))) unsigned int*)g,
      (__attribute__((address_space(3))) unsigned int*)lds,
      16, 0, 0);
}

// wave-local waits (gfx9 encoding: vm [3:0]|[15:14], exp [6:4], lgkm [11:8])
#define WAIT_VM8()   __builtin_amdgcn_s_waitcnt(0x0F78)
#define WAIT_VM4()   __builtin_amdgcn_s_waitcnt(0x0F74)
#define WAIT_VM0()   __builtin_amdgcn_s_waitcnt(0x0F70)
#define WAIT_LGKM0() __builtin_amdgcn_s_waitcnt(0xC07F)

#define NNODES 32000
#define NEDGES 80000
#define NGRAPH 1000

#define MFMA_F16 __builtin_amdgcn_mfma_f32_16x16x32_f16

// ---------- dtype detect ----------
__global__ __launch_bounds__(256) void detect_kernel(
    const unsigned short* __restrict__ nf, int* __restrict__ flag) {
  __shared__ float sm[256];
  float m = 0.f;
  for (int i = threadIdx.x; i < 4096; i += 256) {
    float v = fabsf(bf2f(nf[i]));
    if (isfinite(v)) m = fmaxf(m, v);
    else m = 1e30f;
  }
  sm[threadIdx.x] = m;
  __syncthreads();
  if (threadIdx.x == 0) {
    float mm = 0.f;
    for (int i = 0; i < 256; ++i) mm = fmaxf(mm, sm[i]);
    flag[0] = (mm > 1e6f) ? 1 : 0;
  }
}

// ---------- prep: GRU weights -> fp16 [192][64] (j-major, transposed) ----------
__global__ __launch_bounds__(256) void prep_kernel(
    const int* __restrict__ dflag,
    const void* __restrict__ Wx, const void* __restrict__ Wh,
    const void* __restrict__ bx, const void* __restrict__ bh,
    const void* __restrict__ bconv,
    unsigned short* __restrict__ WxH, unsigned short* __restrict__ WhH,
    float* __restrict__ bxf, float* __restrict__ bhf, float* __restrict__ bconvf) {
  bool f32 = dflag[0] != 0;
  int idx = blockIdx.x * 256 + threadIdx.x;   // grid 48 -> 12288 = 192*64
  int j = idx >> 6, k = idx & 63;
  WxH[idx] = f2h(ldi(Wx, k * 192 + j, f32));
  WhH[idx] = f2h(ldi(Wh, k * 192 + j, f32));
  if (idx < 192) { bxf[idx] = ldi(bx, idx, f32); bhf[idx] = ldi(bh, idx, f32); }
  if (idx < 64) bconvf[idx] = ldi(bconv, idx, f32);
}

// ---------- node projection: h = relu(nf @ Wp + bp) ----------
__global__ __launch_bounds__(256) void nodeproj_kernel(
    const int* __restrict__ dflag,
    const void* __restrict__ nf, const void* __restrict__ Wp,
    const void* __restrict__ bp, float* __restrict__ hstate) {
  bool f32 = dflag[0] != 0;
  int lane = threadIdx.x & 63;
  int n = blockIdx.x * 4 + (threadIdx.x >> 6);
  float acc = ldi(bp, lane, f32);
  for (int k = 0; k < 74; ++k)
    acc += ldi(nf, (long)n * 74 + k, f32) * ldi(Wp, k * 64 + lane, f32);
  hstate[n * 64 + lane] = fmaxf(acc, 0.0f);
}

// ---------- We2Hsw: fp16, layout [d][o][cc][j], cc = (k/8) ^ (o&15) ----------
__global__ __launch_bounds__(256) void we2h_kernel(
    const int* __restrict__ dflag,
    const void* __restrict__ We2, unsigned short* __restrict__ We2Hsw) {
  bool f32 = dflag[0] != 0;
  int idx = blockIdx.x * 256 + threadIdx.x;  // grid 2048 -> 524288
  int j = idx & 7;
  int cc = (idx >> 3) & 15;
  int o = (idx >> 7) & 63;
  int d = idx >> 13;
  int k = ((cc ^ (o & 15)) << 3) | j;
  We2Hsw[idx] = f2h(ldi(We2, (long)k * 4096 + d * 64 + o, f32));
}

// ---------- CSR build (once per launch; dst is launch-invariant) ----------
__global__ __launch_bounds__(256) void count_kernel(
    const int* __restrict__ dst, int* __restrict__ cnt) {
  int e = blockIdx.x * 256 + threadIdx.x;
  if (e < NEDGES) atomicAdd(&cnt[dst[e]], 1);
}

__global__ __launch_bounds__(256) void scan_kernel(
    const int* __restrict__ cnt, int* __restrict__ row_ptr, int* __restrict__ cur) {
  __shared__ int part[256];
  int t = threadIdx.x;
  int base = t * 125;              // 256*125 = 32000
  int s = 0;
  for (int i = 0; i < 125; ++i) s += cnt[base + i];
  part[t] = s;
  __syncthreads();
  if (t == 0) {
    int run = 0;
    for (int i = 0; i < 256; ++i) { int v = part[i]; part[i] = run; run += v; }
  }
  __syncthreads();
  int run = part[t];
  for (int i = 0; i < 125; ++i) {
    row_ptr[base + i] = run;
    cur[base + i] = run;
    run += cnt[base + i];
  }
  if (t == 255) row_ptr[32000] = run;
}

__global__ __launch_bounds__(256) void fill_kernel(
    const int* __restrict__ dst, int* __restrict__ cur, int* __restrict__ eidx) {
  int e = blockIdx.x * 256 + threadIdx.x;
  if (e < NEDGES) { int p = atomicAdd(&cur[dst[e]], 1); eidx[p] = e; }
}

// ---------- fused message passing: 64 edges/block, depth-3 vmcnt pipeline -------
// (r12 version — measured best: 137.5 us/step, 320K LDS conflicts)
__global__ __launch_bounds__(256, 2) void msg_fused_kernel(
    const int* __restrict__ dflag,
    const float* __restrict__ hstate,
    const void* __restrict__ ef, const void* __restrict__ We1,
    const void* __restrict__ be1, const void* __restrict__ be2,
    const unsigned short* __restrict__ We2Hsw,
    const int* __restrict__ src, const int* __restrict__ eidx,
    float* __restrict__ msgbuf) {
  bool f32 = dflag[0] != 0;
  __shared__ __align__(16) unsigned short u_s[64][136];   // 17408 B (aliased as buf2)
  __shared__ float h_s[64][65];                           // 16640 B
  __shared__ __align__(8) unsigned short be2h[64][72];    // 9216 B (fp16)
  __shared__ int ssrc[64];
  __shared__ int seidx[64];
  __shared__ __align__(16) unsigned short wbuf[2][8192];  // 32768 B
  float* ef_s = (float*)&wbuf[0][0];        // 768 floats  (dead before DMA)
  float* we1_s = (float*)&wbuf[0][2048];    // 1536 floats
  float* be1_s = (float*)&wbuf[1][0];       // 128 floats

  int t = threadIdx.x;
  int e0 = blockIdx.x * 64;                 // 1250 blocks
  int lane = t & 63, w = t >> 6;

  if (t < 64) { int e = eidx[e0 + t]; seidx[t] = e; ssrc[t] = src[e]; }
  for (int i = t; i < 1536; i += 256) we1_s[i] = ldi(We1, i, f32);
  if (t < 128) be1_s[t] = ldi(be1, t, f32);
  for (int i = t; i < 4096; i += 256) be2h[i >> 6][i & 63] = f2h(ldi(be2, i, f32));
  __syncthreads();
  for (int i = t; i < 768; i += 256) {
    int slot = i / 12, k = i - slot * 12;
    ef_s[i] = ldi(ef, (long)seidx[slot] * 12 + k, f32);
  }
  __syncthreads();

#pragma unroll
  for (int i = 0; i < 32; ++i) {            // 8192 = 64 edges x 128 cols
    int idx = t + i * 256;
    int row = idx >> 7, col = idx & 127;
    float acc = be1_s[col];
#pragma unroll
    for (int k = 0; k < 12; ++k) acc += ef_s[row * 12 + k] * we1_s[k * 128 + col];
    u_s[row][col] = f2h(fmaxf(acc, 0.f));
  }
#pragma unroll
  for (int i = 0; i < 16; ++i) {            // 4096 = 64 rows x 64 cols
    int idx = t + i * 256;
    int row = idx >> 6, col = idx & 63;
    h_s[row][col] = hstate[(size_t)ssrc[row] * 64 + col];
  }
  __syncthreads();                          // scratch (wbuf) dead from here

  // ---- B fragments from u_s (must complete before u_s is reused as buf2) ----
  int o0 = w * 16;
  int c = lane & 15, q = lane >> 4;
  HFrag ub[4][4];
#pragma unroll
  for (int g = 0; g < 4; ++g)
#pragma unroll
    for (int kk = 0; kk < 4; ++kk)
      ub[g][kk].u4 = *(const uint4*)&u_s[g * 16 + c][q * 8 + kk * 32];
  floatx4 msg[4];
#pragma unroll
  for (int g = 0; g < 4; ++g) msg[g] = (floatx4){0.f, 0.f, 0.f, 0.f};
  int rowb = (o0 + c) * 16;

  // three slice buffers (no pointer array — runtime select below)
  unsigned short* buf0 = &wbuf[0][0];
  unsigned short* buf1 = &wbuf[1][0];
  unsigned short* buf2 = &u_s[0][0];

  // ---- prefetch slices 0,1 into wbuf[0..1] (wave-private quarters) ----
  {
    const unsigned short* g0 = We2Hsw + w * 2048 + lane * 8;
    unsigned short* l0 = buf0 + w * 2048;
    dma16(l0, g0); dma16(l0 + 512, g0 + 512);
    dma16(l0 + 1024, g0 + 1024); dma16(l0 + 1536, g0 + 1536);
    const unsigned short* g1 = g0 + 8192;
    unsigned short* l1 = buf1 + w * 2048;
    dma16(l1, g1); dma16(l1 + 512, g1 + 512);
    dma16(l1 + 1024, g1 + 1024); dma16(l1 + 1536, g1 + 1536);
  }
  __syncthreads();                          // all waves' ub loads drained -> u_s dead
  {
    const unsigned short* g2 = We2Hsw + 2 * 8192 + w * 2048 + lane * 8;
    unsigned short* l2 = buf2 + w * 2048;
    dma16(l2, g2); dma16(l2 + 512, g2 + 512);
    dma16(l2 + 1024, g2 + 1024); dma16(l2 + 1536, g2 + 1536);
  }

  // ---- depth-3 d-loop (no barriers) ----
  int m3 = 0;                               // rotating buffer index = d mod 3
  for (int d = 0; d < 64; ++d) {
    if (d <= 61) WAIT_VM8();                // slice d's 4 DMAs complete
    else if (d == 62) WAIT_VM4();
    else WAIT_VM0();
    unsigned short* wb = (m3 == 0) ? buf0 : (m3 == 1) ? buf1 : buf2;
    HFrag a0, a1, a2, a3;
    a0.u4 = *(const uint4*)&wb[(rowb + ((0 * 4 + q) ^ c)) * 8];
    a1.u4 = *(const uint4*)&wb[(rowb + ((1 * 4 + q) ^ c)) * 8];
    a2.u4 = *(const uint4*)&wb[(rowb + ((2 * 4 + q) ^ c)) * 8];
    a3.u4 = *(const uint4*)&wb[(rowb + ((3 * 4 + q) ^ c)) * 8];
    WAIT_LGKM0();                           // A-frags in regs before buffer reuse
    if (d + 3 < 64) {
      const unsigned short* g = We2Hsw + (d + 3) * 8192 + w * 2048 + lane * 8;
      unsigned short* l = wb + w * 2048;
      dma16(l, g); dma16(l + 512, g + 512);
      dma16(l + 1024, g + 1024); dma16(l + 1536, g + 1536);
    }
    HS b0, b1, b2v, b3;
    const unsigned short* bp = &be2h[d][o0 + q * 4];
    b0.u = bp[0]; b1.u = bp[1]; b2v.u = bp[2]; b3.u = bp[3];
    float be0 = (float)b0.h, be1v = (float)b1.h, be2f = (float)b2v.h, be3 = (float)b3.h;
#pragma unroll
    for (int g = 0; g < 4; ++g) {
      floatx4 wv = {0.f, 0.f, 0.f, 0.f};
      wv = MFMA_F16(a0.v, ub[g][0].v, wv, 0, 0, 0);
      wv = MFMA_F16(a1.v, ub[g][1].v, wv, 0, 0, 0);
      wv = MFMA_F16(a2.v, ub[g][2].v, wv, 0, 0, 0);
      wv = MFMA_F16(a3.v, ub[g][3].v, wv, 0, 0, 0);
      float hv = h_s[g * 16 + c][d];
      msg[g][0] += hv * (wv[0] + be0);
      msg[g][1] += hv * (wv[1] + be1v);
      msg[g][2] += hv * (wv[2] + be2f);
      msg[g][3] += hv * (wv[3] + be3);
    }
    m3 = (m3 == 2) ? 0 : m3 + 1;
  }

#pragma unroll
  for (int g = 0; g < 4; ++g) {
    int slot = g * 16 + c;
    float4 st;
    st.x = msg[g][0]; st.y = msg[g][1]; st.z = msg[g][2]; st.w = msg[g][3];
    *(float4*)(msgbuf + (size_t)(e0 + slot) * 64 + o0 + q * 4) = st;
  }
}

// ---------- GRU step: MFMA gates (fp16, X hi/lo split) + fused CSR gather ------
__global__ __launch_bounds__(256, 2) void gru_kernel(
    float* __restrict__ hstate, const float* __restrict__ msgbuf,
    const int* __restrict__ row_ptr,
    const unsigned short* __restrict__ WxH, const unsigned short* __restrict__ WhH,
    const float* __restrict__ bxf, const float* __restrict__ bhf,
    const float* __restrict__ bconvf) {
  __shared__ __align__(16) unsigned short Xhi[64][72];   // 9216 B
  __shared__ __align__(16) unsigned short Xlo[64][72];   // 9216 B
  __shared__ __align__(16) unsigned short Hh[64][72];    // 9216 B
  __shared__ unsigned short SRZ[128][68];                // 17408 B (fp16 sig(r/z))
  __shared__ float GXn[64][66];                          // 16896 B
  __shared__ float GHn[64][66];                          // 16896 B
  int t = threadIdx.x;
  int nb = blockIdx.x * 64;                              // 500 blocks

#pragma unroll
  for (int i = 0; i < 16; ++i) {
    int idx = t + i * 256;
    int n = idx >> 6, c = idx & 63;
    int node = nb + n;
    float a = bconvf[c];
    int p0 = row_ptr[node], p1 = row_ptr[node + 1];
    for (int p = p0; p < p1; ++p) a += msgbuf[(size_t)p * 64 + c];
    a = fmaxf(a, 0.f);
    HS hi; hi.h = (_Float16)a;
    Xhi[n][c] = hi.u;
    Xlo[n][c] = f2h(a - (float)hi.h);
    Hh[n][c] = f2h(hstate[(size_t)node * 64 + c]);
  }
  __syncthreads();

  int lane = t & 63, w = t >> 6;
  int c16 = lane & 15, q = lane >> 4;
  floatx4 gx[3][4], gh[3][4];
#pragma unroll
  for (int jt = 0; jt < 3; ++jt)
#pragma unroll
    for (int nt = 0; nt < 4; ++nt) {
      gx[jt][nt] = (floatx4){0.f, 0.f, 0.f, 0.f};
      gh[jt][nt] = (floatx4){0.f, 0.f, 0.f, 0.f};
    }
#pragma unroll
  for (int kc = 0; kc < 2; ++kc) {
    int kof = kc * 32 + q * 8;
    HFrag ax[3], ah[3];
#pragma unroll
    for (int jt = 0; jt < 3; ++jt) {
      long off = (long)((w * 3 + jt) * 16 + c16) * 64 + kof;
      ax[jt].u4 = *(const uint4*)(WxH + off);
      ah[jt].u4 = *(const uint4*)(WhH + off);
    }
    HFrag bxh[4], bxl[4], bhf_[4];
#pragma unroll
    for (int nt = 0; nt < 4; ++nt) {
      int n = nt * 16 + c16;
      bxh[nt].u4 = *(const uint4*)&Xhi[n][kof];
      bxl[nt].u4 = *(const uint4*)&Xlo[n][kof];
      bhf_[nt].u4 = *(const uint4*)&Hh[n][kof];
    }
#pragma unroll
    for (int jt = 0; jt < 3; ++jt)
#pragma unroll
      for (int nt = 0; nt < 4; ++nt) {
        gx[jt][nt] = MFMA_F16(ax[jt].v, bxh[nt].v, gx[jt][nt], 0, 0, 0);
        gx[jt][nt] = MFMA_F16(ax[jt].v, bxl[nt].v, gx[jt][nt], 0, 0, 0);
        gh[jt][nt] = MFMA_F16(ah[jt].v, bhf_[nt].v, gh[jt][nt], 0, 0, 0);
      }
  }

#pragma unroll
  for (int jt = 0; jt < 3; ++jt) {
#pragma unroll
    for (int rr = 0; rr < 4; ++rr) {
      int j = (w * 3 + jt) * 16 + q * 4 + rr;
      float bxv = bxf[j], bhv = bhf[j];
#pragma unroll
      for (int nt = 0; nt < 4; ++nt) {
        int n = nt * 16 + c16;
        float vx = gx[jt][nt][rr] + bxv;
        float vh = gh[jt][nt][rr] + bhv;
        if (j < 128) {
          SRZ[j][n] = f2h(sigmf(vx + vh));
        } else {
          GXn[j - 128][n] = vx;
          GHn[j - 128][n] = vh;
        }
      }
    }
  }
  __syncthreads();

#pragma unroll
  for (int i = 0; i < 16; ++i) {
    int idx = t + i * 256;
    int n = idx >> 6, f = idx & 63;
    float r = h2f(SRZ[f][n]);
    float z = h2f(SRZ[64 + f][n]);
    float ng = tanhf(GXn[f][n] + r * GHn[f][n]);
    size_t gi = (size_t)(nb + n) * 64 + f;
    float ho = hstate[gi];
    hstate[gi] = (1.0f - z) * ng + z * ho;
  }
}

// ---------- Set2Set fused x6 + head: per-graph state lives in LDS ----------
// Per-graph state (q_star, hs, cs) is private and hstate is read-only here,
// so all 6 Set2Set iterations + the prediction head run in ONE kernel.
__global__ __launch_bounds__(256) void s2s6_kernel(
    const int* __restrict__ dflag,
    const float* __restrict__ hstate,
    const void* Wx0, const void* Wh0, const void* bx0, const void* bh0,
    const void* Wx1, const void* Wh1, const void* bx1, const void* bh1,
    const void* Wx2, const void* Wh2, const void* bx2, const void* bh2,
    const void* __restrict__ Wout1, const void* __restrict__ bout1,
    const void* __restrict__ Wout2, const void* __restrict__ bout2,
    float* __restrict__ out) {
  bool f32 = dflag[0] != 0;
  __shared__ float xq[4][128];        // q_star per graph
  __shared__ float hh[4][64];
  __shared__ float gates[4][256];
  __shared__ float al[4][32];
  __shared__ float hsvf[768];         // 3 layers x 4 graphs x 64
  __shared__ float csvf[768];
  int g0 = blockIdx.x * 4;
  int t = threadIdx.x;
  const void* Wx[3] = {Wx0, Wx1, Wx2};
  const void* Wh[3] = {Wh0, Wh1, Wh2};
  const void* bx[3] = {bx0, bx1, bx2};
  const void* bh[3] = {bh0, bh1, bh2};

  // zero-init state
  for (int i = t; i < 512; i += 256) xq[i >> 7][i & 127] = 0.f;
  for (int i = t; i < 768; i += 256) { hsvf[i] = 0.f; csvf[i] = 0.f; }
  __syncthreads();

  int gg = t >> 6, tt = t & 63;
  int g = g0 + gg;

  for (int s = 0; s < 6; ++s) {
    // ---- 3-layer LSTM ----
    for (int l = 0; l < 3; ++l) {
      int fi = (l == 0) ? 128 : 64;
      hh[gg][tt] = hsvf[l * 256 + t];
      __syncthreads();
      float bsum = ldi(bx[l], t, f32) + ldi(bh[l], t, f32);
      float a0 = bsum, a1 = bsum, a2 = bsum, a3 = bsum;
      for (int k = 0; k < fi; ++k) {
        float wv = ldi(Wx[l], (long)k * 256 + t, f32);
        a0 += xq[0][k] * wv;
        a1 += xq[1][k] * wv;
        a2 += xq[2][k] * wv;
        a3 += xq[3][k] * wv;
      }
      for (int k = 0; k < 64; ++k) {
        float wv = ldi(Wh[l], (long)k * 256 + t, f32);
        a0 += hh[0][k] * wv;
        a1 += hh[1][k] * wv;
        a2 += hh[2][k] * wv;
        a3 += hh[3][k] * wv;
      }
      gates[0][t] = a0; gates[1][t] = a1; gates[2][t] = a2; gates[3][t] = a3;
      __syncthreads();
      {
        float ig = sigmf(gates[gg][tt]);
        float fg = sigmf(gates[gg][64 + tt]);
        float gv = tanhf(gates[gg][128 + tt]);
        float og = sigmf(gates[gg][192 + tt]);
        int ci = l * 256 + t;
        float cc = fg * csvf[ci] + ig * gv;
        float hn = og * tanhf(cc);
        csvf[ci] = cc;
        hsvf[ci] = hn;
        xq[gg][tt] = hn;
      }
      __syncthreads();
    }
    // ---- attention: one wave per graph ----
    {
      int n = tt & 31, half = tt >> 5;
      const float* hrow = hstate + (size_t)(g * 32 + n) * 64 + half * 32;
      const float* qp = &xq[gg][half * 32];
      float p = 0.f;
#pragma unroll
      for (int k = 0; k < 32; ++k) p += hrow[k] * qp[k];
      p += __shfl_xor(p, 32, 64);
      if (half == 0) {
        float m = p;
#pragma unroll
        for (int s2 = 1; s2 < 32; s2 <<= 1) m = fmaxf(m, __shfl_xor(m, s2, 32));
        float e = expf(p - m);
        float sum = e;
#pragma unroll
        for (int s2 = 1; s2 < 32; s2 <<= 1) sum += __shfl_xor(sum, s2, 32);
        al[gg][n] = e / sum;
      }
    }
    float acc = 0.f;
#pragma unroll 8
    for (int n = 0; n < 32; ++n)
      acc += al[gg][n] * hstate[(size_t)(g * 32 + n) * 64 + tt];
    xq[gg][64 + tt] = acc;                   // readout half of q_star
    __syncthreads();                         // visible to all graphs' gemm next iter
  }

  // ---- head ----
  float acc = ldi(bout1, tt, f32);
#pragma unroll 16
  for (int k = 0; k < 128; ++k) acc += xq[gg][k] * ldi(Wout1, k * 64 + tt, f32);
  acc = fmaxf(acc, 0.0f);
  float p = acc * ldi(Wout2, tt, f32);
#pragma unroll
  for (int m = 1; m < 64; m <<= 1) p += __shfl_xor(p, m, 64);
  if (tt == 0) out[g] = p + ldi(bout2, 0, f32);
  out[1000 + g * 128 + tt] = xq[gg][tt];
  out[1000 + g * 128 + 64 + tt] = xq[gg][64 + tt];
}

// ---------- launch ----------
extern "C" void kernel_launch(void* const* d_in, const int* in_sizes, int n_in,
                              void* d_out, int out_size, void* d_ws, size_t ws_size,
                              hipStream_t stream) {
  (void)in_sizes; (void)n_in; (void)out_size; (void)ws_size;
  const void* node_feats = d_in[0];
  const void* edge_feats = d_in[1];
  const int* src = (const int*)d_in[2];
  const int* dst = (const int*)d_in[3];
  const void* Wp = d_in[5];
  const void* bp = d_in[6];
  const void* We1 = d_in[7];
  const void* be1 = d_in[8];
  const void* We2 = d_in[9];
  const void* be2 = d_in[10];
  const void* b_conv = d_in[11];
  const void* gWx = d_in[12];
  const void* gWh = d_in[13];
  const void* gbx = d_in[14];
  const void* gbh = d_in[15];
  const void* Wout1 = d_in[16];
  const void* bout1 = d_in[17];
  const void* Wout2 = d_in[18];
  const void* bout2 = d_in[19];

  // workspace layout (~31 MB; proven-mapped region >= 44.5 MB)
  int* dflag = (int*)d_ws;                                    // 64 ints reserved
  float* hstate = (float*)d_ws + 64;                          // 32000*64 f32
  float* msgbuf = hstate + NNODES * 64;                       // 80000*64 f32
  unsigned short* We2Hsw = (unsigned short*)(msgbuf + (size_t)NEDGES * 64); // 524288 fp16
  unsigned short* WxH = We2Hsw + 524288;                      // 12288 fp16
  unsigned short* WhH = WxH + 12288;                          // 12288 fp16
  float* bxf = (float*)(WhH + 12288);                         // 192
  float* bhf = bxf + 192;                                     // 192
  float* bconvf = bhf + 192;                                  // 64
  int* row_ptr = (int*)(bconvf + 64);                         // 32001
  int* cur = row_ptr + 32001;                                 // 32000
  int* cnt = cur + 32000;                                     // 32000
  int* eidx = cnt + 32000;                                    // 80000

  (void)hipMemsetAsync(cnt, 0, (size_t)NNODES * sizeof(int), stream);

  detect_kernel<<<1, 256, 0, stream>>>((const unsigned short*)node_feats, dflag);
  prep_kernel<<<48, 256, 0, stream>>>(dflag, gWx, gWh, gbx, gbh, b_conv,
                                      WxH, WhH, bxf, bhf, bconvf);
  nodeproj_kernel<<<NNODES / 4, 256, 0, stream>>>(dflag, node_feats, Wp, bp, hstate);
  we2h_kernel<<<2048, 256, 0, stream>>>(dflag, We2, We2Hsw);

  count_kernel<<<(NEDGES + 255) / 256, 256, 0, stream>>>(dst, cnt);
  scan_kernel<<<1, 256, 0, stream>>>(cnt, row_ptr, cur);
  fill_kernel<<<(NEDGES + 255) / 256, 256, 0, stream>>>(dst, cur, eidx);

  for (int step = 0; step < 6; ++step) {
    msg_fused_kernel<<<NEDGES / 64, 256, 0, stream>>>(
        dflag, hstate, edge_feats, We1, be1, be2, We2Hsw, src, eidx, msgbuf);
    gru_kernel<<<NNODES / 64, 256, 0, stream>>>(hstate, msgbuf, row_ptr,
                                                WxH, WhH, bxf, bhf, bconvf);
  }
  s2s6_kernel<<<NGRAPH / 4, 256, 0, stream>>>(dflag, hstate,
      d_in[20], d_in[21], d_in[22], d_in[23],
      d_in[24], d_in[25], d_in[26], d_in[27],
      d_in[28], d_in[29], d_in[30], d_in[31],
      Wout1, bout1, Wout2, bout2, (float*)d_out);
}